// Round 4
// baseline (339.304 us; speedup 1.0000x reference)
//
#include <hip/hip_runtime.h>
#include <hip/hip_fp16.h>

#define N_NODES 100000
#define N_EDGES 1600000
#define DIN 24
#define DH 64
#define DOUT 12
#define NEG_SLOPE 0.01f
#define NG 32                      // edge chunks
#define EPG (N_EDGES / NG)         // 50000 edges per chunk
#define NS 7                       // node slices for LDS hist
#define SLICE_N 16384              // nodes per slice (16 KB byte counters)
#define NTOT (NG * N_NODES)        // 3.2M (chunk,node) byte counters
#define SCAN_BLK 4096
#define LDSW 72

// role block counts
#define NB_HIST (NS * NG)                        // 224 (1024-thread blocks in D1)
#define NB_EMBED (((N_NODES * DH) + 8191) / 8192)       // 782 (grid-stride x8)
#define NB_SUMDEG ((N_NODES + 255) / 256)               // 391
#define NB_SCAN1N ((N_NODES + SCAN_BLK - 1) / SCAN_BLK) // 25
#define NB_SCAT ((N_EDGES + 255) / 256)          // 6250 (1 edge/thread)
#define NB_NODE ((N_NODES + 63) / 64)            // 1563 tiles of 64 nodes
#define NB_NODE_T ((NB_NODE + 1) / 2)            // 782 blocks, 2 tiles each
#define NB_AGG ((N_NODES + 7) / 8)               // 12500

typedef _Float16 half8_t __attribute__((ext_vector_type(8)));
typedef float floatx4 __attribute__((ext_vector_type(4)));

// ---------------- role bodies ----------------
__device__ __forceinline__ void dev_consts(const float* emb_e_W, const float* emb_e_b,
                                           const float* attn1, const float* attn2,
                                           float* consts) {
    int lane = threadIdx.x;
    if (lane >= 64) return;
    float w = emb_e_W[lane], b = emb_e_b[lane];
    float a1 = attn1[2 * DH + lane], a2 = attn2[2 * DH + lane];
    float c11 = w * a1, c01 = b * a1, c12 = w * a2, c02 = b * a2;
    for (int off = 32; off; off >>= 1) {
        c11 += __shfl_down(c11, off);
        c01 += __shfl_down(c01, off);
        c12 += __shfl_down(c12, off);
        c02 += __shfl_down(c02, off);
    }
    if (lane == 0) {
        consts[0] = c11; consts[1] = c01; consts[2] = c12; consts[3] = c02;
    }
}

// slice-LDS histogram + rank capture, ZERO global atomics.
__device__ __forceinline__ void dev_hist(int bid, const int* dst,
                                         unsigned char* deg, unsigned char* rank) {
    __shared__ unsigned cnt[SLICE_N / 4];   // 16 KB byte-packed
    int s = bid % NS, c = bid / NS;
    for (int i = threadIdx.x; i < SLICE_N / 4; i += 1024) cnt[i] = 0;
    __syncthreads();
    int nbase = s * SLICE_N;
    int start = c * EPG, end = start + EPG;
    for (int i = start + threadIdx.x; i < end; i += 1024) {
        int local = dst[i] - nbase;
        if ((unsigned)local < SLICE_N) {
            unsigned sh = (unsigned)(local & 3) * 8u;
            unsigned old = atomicAdd(&cnt[local >> 2], 1u << sh);  // LDS atomic
            rank[i] = (unsigned char)((old >> sh) & 255u);
        }
    }
    __syncthreads();
    int nmax = N_NODES - nbase;
    if (nmax > SLICE_N) nmax = SLICE_N;
    unsigned* dw = (unsigned*)(deg + (size_t)c * N_NODES + nbase);
    for (int l = threadIdx.x; l < (nmax >> 2); l += 1024) dw[l] = cnt[l];
}

// grid-stride x8 embed
__device__ __forceinline__ void dev_embed(int bid, const float* feats, const float* W,
                                          const float* b, float* h) {
    for (int r = 0; r < 8; ++r) {
        int idx = bid * 8192 + r * 1024 + threadIdx.x;
        if (idx >= N_NODES * DH) return;
        int n = idx >> 6, o = idx & 63;
        const float* f = feats + n * DIN;
        const float* w = W + o * DIN;
        float acc = b[o];
#pragma unroll
        for (int k = 0; k < DIN; ++k) acc += f[k] * w[k];
        h[idx] = acc;
    }
}

__device__ __forceinline__ void dev_scan1(int bid, const int* in, int* out,
                                          int* part, int n) {
    __shared__ int lds[256];
    int t = threadIdx.x;
    int base = bid * SCAN_BLK + t * 16;
    int v[16];
    int s = 0;
#pragma unroll
    for (int i = 0; i < 16; ++i) {
        int idx = base + i;
        v[i] = (idx < n) ? in[idx] : 0;
        s += v[i];
    }
    lds[t] = s;
    __syncthreads();
    for (int off = 1; off < 256; off <<= 1) {
        int y = (t >= off) ? lds[t - off] : 0;
        __syncthreads();
        lds[t] += y;
        __syncthreads();
    }
    int run = lds[t] - s;
#pragma unroll
    for (int i = 0; i < 16; ++i) {
        int idx = base + i;
        if (idx < n) out[idx] = run;
        run += v[i];
    }
    if (t == 255) part[bid] = lds[255];
}

// exclusive scan of part[0..nblk) + row_offN[N_NODES] tail fixup
__device__ __forceinline__ void dev_scan2(int* part, int nblk, int* row_offN) {
    __shared__ int lds2[256];
    int t = threadIdx.x;
    int v[4];
    int s = 0;
#pragma unroll
    for (int i = 0; i < 4; ++i) {
        int idx = t * 4 + i;
        v[i] = (idx < nblk) ? part[idx] : 0;
        s += v[i];
    }
    lds2[t] = s;
    __syncthreads();
    for (int off = 1; off < 256; off <<= 1) {
        int y = (t >= off) ? lds2[t - off] : 0;
        __syncthreads();
        lds2[t] += y;
        __syncthreads();
    }
    int run = lds2[t] - s;
#pragma unroll
    for (int i = 0; i < 4; ++i) {
        int idx = t * 4 + i;
        if (idx < nblk) part[idx] = run;
        run += v[i];
    }
    if (row_offN) {
        __syncthreads();
        if (t == 0) row_offN[N_NODES] = N_EDGES - part[N_NODES >> 12];
    }
}

// degN + per-node chunk prefix (byte)
__device__ __forceinline__ void dev_sumdeg(int bid, const unsigned char* degB,
                                           int* degN, unsigned char* chunkOff) {
    int n = bid * 256 + threadIdx.x;
    if (n >= N_NODES) return;
    int run = 0;
#pragma unroll
    for (int g = 0; g < NG; ++g) {
        size_t idx = (size_t)g * N_NODES + n;
        int v = (int)degB[idx];
        chunkOff[idx] = (unsigned char)run;
        run += v;
    }
    degN[n] = run;
}

// MFMA node GEMM, multi-tile: stage weights once, then grid-stride 2 tiles.
// No __syncthreads inside the tile loop (staging barrier only).
__device__ __forceinline__ void dev_nodeM(int bid, int stride, const float* h,
                                          const float* Wself, const float* Wfunc,
                                          const float* attn,
                                          __half* zh, float* hs,
                                          float* s_src, float* s_dst) {
    __shared__ _Float16 lds[2 * 64 * LDSW];
    int tid = threadIdx.x;
    for (int idx = tid; idx < 2 * 64 * 64; idx += 256) {
        int mat = idx >> 12, rem = idx & 4095;
        int o = rem >> 6, k = rem & 63;
        float v = mat ? Wfunc[rem] : Wself[rem];
        lds[(mat * 64 + o) * LDSW + k] = (_Float16)v;
    }
    __syncthreads();

    int wave = tid >> 6, lane = tid & 63;
    int quad = lane >> 4, lm = lane & 15;
    float asv[4], adv[4];
#pragma unroll
    for (int t = 0; t < 4; ++t) {
        asv[t] = attn[t * 16 + lm];
        adv[t] = attn[DH + t * 16 + lm];
    }
    const _Float16* bS = lds;
    const _Float16* bF = lds + 64 * LDSW;

    for (int tb = bid; tb < NB_NODE; tb += stride) {
        int n0 = (tb * 4 + wave) * 16;
        if (n0 >= N_NODES) continue;

        half8_t afrag[2];
        {
            const float4* hrow = (const float4*)(h + (size_t)(n0 + lm) * DH);
#pragma unroll
            for (int ks = 0; ks < 2; ++ks) {
                float4 p0 = hrow[ks * 8 + quad * 2];
                float4 p1 = hrow[ks * 8 + quad * 2 + 1];
                half8_t a;
                a[0] = (_Float16)p0.x; a[1] = (_Float16)p0.y;
                a[2] = (_Float16)p0.z; a[3] = (_Float16)p0.w;
                a[4] = (_Float16)p1.x; a[5] = (_Float16)p1.y;
                a[6] = (_Float16)p1.z; a[7] = (_Float16)p1.w;
                afrag[ks] = a;
            }
        }

        floatx4 accS[4], accF[4];
#pragma unroll
        for (int t = 0; t < 4; ++t) { accS[t] = (floatx4)0.f; accF[t] = (floatx4)0.f; }

#pragma unroll
        for (int t = 0; t < 4; ++t) {
            int o = t * 16 + lm;
#pragma unroll
            for (int ks = 0; ks < 2; ++ks) {
                int hoff = o * LDSW + ks * 32 + quad * 8;
                half8_t b1 = *(const half8_t*)(bS + hoff);
                half8_t b2 = *(const half8_t*)(bF + hoff);
                accS[t] = __builtin_amdgcn_mfma_f32_16x16x32_f16(afrag[ks], b1, accS[t], 0, 0, 0);
                accF[t] = __builtin_amdgcn_mfma_f32_16x16x32_f16(afrag[ks], b2, accF[t], 0, 0, 0);
            }
        }

        float ps[4] = {0.f, 0.f, 0.f, 0.f}, pd[4] = {0.f, 0.f, 0.f, 0.f};
#pragma unroll
        for (int t = 0; t < 4; ++t) {
#pragma unroll
            for (int r = 0; r < 4; ++r) {
                int node = n0 + quad * 4 + r;
                float zv = accF[t][r];
                zh[(size_t)node * DH + t * 16 + lm] = __float2half(zv);
                hs[(size_t)node * DH + t * 16 + lm] = accS[t][r];
                ps[r] += zv * asv[t];
                pd[r] += zv * adv[t];
            }
        }
#pragma unroll
        for (int r = 0; r < 4; ++r) {
            float p1 = ps[r], p2 = pd[r];
            for (int off = 8; off; off >>= 1) {
                p1 += __shfl_xor(p1, off);
                p2 += __shfl_xor(p2, off);
            }
            if (lm == 0) {
                s_src[n0 + quad * 4 + r] = p1;
                s_dst[n0 + quad * 4 + r] = p2;
            }
        }
    }
}

// ---------------- fused dispatches ----------------
// D1 (1024 thr): consts | hist(slice-LDS, +rank) | embed(grid-stride x8)
__global__ void __launch_bounds__(1024, 2)
k_fuse1(const float* __restrict__ feats, const float* __restrict__ emb_h_W,
        const float* __restrict__ emb_h_b, float* __restrict__ h,
        const int* __restrict__ dst, unsigned char* __restrict__ deg,
        unsigned char* __restrict__ rank,
        const float* __restrict__ emb_e_W, const float* __restrict__ emb_e_b,
        const float* __restrict__ attn1, const float* __restrict__ attn2,
        float* __restrict__ consts) {
    int bid = blockIdx.x;
    if (bid == 0) { dev_consts(emb_e_W, emb_e_b, attn1, attn2, consts); return; }
    bid -= 1;
    if (bid < NB_HIST) { dev_hist(bid, dst, deg, rank); return; }
    dev_embed(bid - NB_HIST, feats, emb_h_W, emb_h_b, h);
}

// D2: sumdeg+chunkOff | node GEMM L1 (rides the otherwise-idle machine;
// depends only on h from D1, not on the scan chain)
__global__ void __launch_bounds__(256, 4)
k_fuse2(const unsigned char* __restrict__ degB, int* __restrict__ degN,
        unsigned char* __restrict__ chunkOff,
        const float* __restrict__ h, const float* __restrict__ Wself1,
        const float* __restrict__ Wfunc1, const float* __restrict__ attn1,
        __half* __restrict__ zh, float* __restrict__ hs,
        float* __restrict__ s_src, float* __restrict__ s_dst) {
    int bid = blockIdx.x;
    if (bid < NB_SUMDEG) { dev_sumdeg(bid, degB, degN, chunkOff); return; }
    dev_nodeM(bid - NB_SUMDEG, NB_NODE_T, h, Wself1, Wfunc1, attn1,
              zh, hs, s_src, s_dst);
}

// D3: scan1N
__global__ void k_prep3(const int* __restrict__ degN, int* __restrict__ row_offN,
                        int* __restrict__ partN) {
    dev_scan1(blockIdx.x, degN, row_offN, partN, N_NODES);
}

// D4: scan2N + tail
__global__ void k_prep4(int* __restrict__ partN, int* __restrict__ row_offN) {
    dev_scan2(partN, NB_SCAN1N, row_offN);
}

// D5: scatter, 1 edge/thread (max TLP for the scattered-load chain)
__global__ void __launch_bounds__(256, 8)
k_scat(const int* __restrict__ src, const int* __restrict__ dst,
       const float* __restrict__ e_w, const unsigned char* __restrict__ rank,
       const int* __restrict__ row_offN, const int* __restrict__ partN,
       const unsigned char* __restrict__ chunkOff, unsigned* __restrict__ csr2) {
    int i = blockIdx.x * 256 + threadIdx.x;
    if (i >= N_EDGES) return;
    int g = i / EPG;
    int d = dst[i];
    unsigned qv = (unsigned)(e_w[i] * 32768.f);
    if (qv > 32767u) qv = 32767u;
    unsigned w = (unsigned)src[i] | (qv << 17);
    int pos = row_offN[d] + partN[d >> 12] + (int)chunkOff[(size_t)g * N_NODES + d]
            + (int)rank[i];
    csr2[pos] = w;
}

// standalone layer-2 node GEMM (2 tiles/block)
__global__ void __launch_bounds__(256, 4)
k_nodeL(const float* __restrict__ h, const float* __restrict__ Wself,
        const float* __restrict__ Wfunc, const float* __restrict__ attn,
        __half* __restrict__ zh, float* __restrict__ hs,
        float* __restrict__ s_src, float* __restrict__ s_dst) {
    dev_nodeM(blockIdx.x, NB_NODE_T, h, Wself, Wfunc, attn, zh, hs, s_src, s_dst);
}

// ---------------- fused edge softmax + aggregation + (optional) final projection --------
__global__ void k_agg(const int* __restrict__ row_off, const int* __restrict__ partN,
                      const unsigned* __restrict__ csr,
                      const float* __restrict__ s_src, const float* __restrict__ s_dstA,
                      const float* __restrict__ consts, int layer,
                      const __half* __restrict__ zh, const float* __restrict__ hsb,
                      float* __restrict__ h,
                      const float* __restrict__ lin_W, const float* __restrict__ lin_b,
                      float* __restrict__ y, int final_layer) {
    int wave = threadIdx.x >> 6, lane = threadIdx.x & 63;
    int half = lane >> 5, hl = lane & 31;
    int eg = (lane >> 3) & 3, c8 = lane & 7;
    int n = blockIdx.x * 8 + wave * 2 + half;
    if (n >= N_NODES) return;
    int rs = row_off[n] + partN[n >> 12];
    int re = row_off[n + 1] + partN[(n + 1) >> 12];
    int deg = re - rs;
    int degO = __shfl_xor(deg, 32);
    int degmax = deg > degO ? deg : degO;

    float c1 = consts[layer * 2 + 0];
    float c0 = consts[layer * 2 + 1];
    float sd = s_dstA[n];

    float acc[8];
#pragma unroll
    for (int k = 0; k < 8; ++k) acc[k] = 0.f;
    float ssl = 0.f;
    int lbase = lane & 32;

    for (int base = 0; base < degmax; base += 32) {
        float ex = 0.f;
        int s0 = 0;
        int idx = base + hl;
        if (idx < deg) {
            unsigned w = csr[rs + idx];
            s0 = (int)(w & 0x1FFFFu);
            float ew = (float)(w >> 17) * (1.f / 32768.f);
            float e = s_src[s0] + sd + ew * c1 + c0;
            e = (e > 0.f) ? e : NEG_SLOPE * e;
            ex = __expf(e);
        }
        ssl += ex;
        int cnt = degmax - base;
        if (cnt > 32) cnt = 32;
#pragma unroll 4
        for (int jb = 0; jb < cnt; jb += 4) {
            int srcl = lbase + jb + eg;
            int sj = __shfl(s0, srcl);
            float exj = __shfl(ex, srcl);
            half8_t zv = *(const half8_t*)(zh + ((size_t)sj << 6) + (c8 << 3));
#pragma unroll
            for (int k = 0; k < 8; ++k) acc[k] += exj * (float)zv[k];
        }
    }
#pragma unroll
    for (int k = 0; k < 8; ++k) {
        acc[k] += __shfl_xor(acc[k], 8);
        acc[k] += __shfl_xor(acc[k], 16);
    }
    ssl += __shfl_xor(ssl, 16); ssl += __shfl_xor(ssl, 8);
    ssl += __shfl_xor(ssl, 4);  ssl += __shfl_xor(ssl, 2);
    ssl += __shfl_xor(ssl, 1);

    const float4* hp = (const float4*)(h + (size_t)n * DH);
    float4 ho0 = hp[c8 * 2], ho1 = hp[c8 * 2 + 1];
    float hold[8] = {ho0.x, ho0.y, ho0.z, ho0.w, ho1.x, ho1.y, ho1.z, ho1.w};
    float hnew[8];
    if (deg == 0) {
#pragma unroll
        for (int k = 0; k < 8; ++k) hnew[k] = hold[k] + fmaxf(hold[k], 0.f);
    } else {
        float rinv = 1.f / ssl;
        const float4* sp = (const float4*)(hsb + (size_t)n * DH);
        float4 hs0 = sp[c8 * 2], hs1 = sp[c8 * 2 + 1];
        float hsv[8] = {hs0.x, hs0.y, hs0.z, hs0.w, hs1.x, hs1.y, hs1.z, hs1.w};
#pragma unroll
        for (int k = 0; k < 8; ++k)
            hnew[k] = hold[k] + fmaxf(hsv[k] + acc[k] * rinv, 0.f);
    }

    if (!final_layer) {
        if (eg == 0) {
            float4* op = (float4*)(h + (size_t)n * DH);
            op[c8 * 2]     = make_float4(hnew[0], hnew[1], hnew[2], hnew[3]);
            op[c8 * 2 + 1] = make_float4(hnew[4], hnew[5], hnew[6], hnew[7]);
        }
    } else {
#pragma unroll
        for (int t = 0; t < 3; ++t) {
            int o = eg * 3 + t;
            const float* wr = lin_W + o * DH + c8 * 8;
            float p = 0.f;
#pragma unroll
            for (int k = 0; k < 8; ++k) p += hnew[k] * wr[k];
            p += __shfl_xor(p, 1); p += __shfl_xor(p, 2); p += __shfl_xor(p, 4);
            if (c8 == 0) y[n * DOUT + o] = p + lin_b[o];
        }
    }
}

extern "C" void kernel_launch(void* const* d_in, const int* in_sizes, int n_in,
                              void* d_out, int out_size, void* d_ws, size_t ws_size,
                              hipStream_t stream) {
    const float* feats   = (const float*)d_in[0];
    const float* e_w     = (const float*)d_in[1];
    const int*   src     = (const int*)d_in[4];
    const int*   dst     = (const int*)d_in[5];
    const float* emb_h_W = (const float*)d_in[6];
    const float* emb_h_b = (const float*)d_in[7];
    const float* emb_e_W = (const float*)d_in[8];
    const float* emb_e_b = (const float*)d_in[9];
    const float* Wself[2] = {(const float*)d_in[10], (const float*)d_in[13]};
    const float* Wfunc[2] = {(const float*)d_in[11], (const float*)d_in[14]};
    const float* attn[2]  = {(const float*)d_in[12], (const float*)d_in[15]};
    const float* lin1_W  = (const float*)d_in[16];
    const float* lin1_b  = (const float*)d_in[17];
    float* y = (float*)d_out;

    char* ws = (char*)d_ws;
    size_t off = 0;
    auto alloc = [&](size_t bytes) {
        void* p = ws + off;
        off += (bytes + 255) & ~(size_t)255;
        return p;
    };
    float*          h        = (float*)alloc((size_t)N_NODES * DH * 4);
    __half*         zh       = (__half*)alloc((size_t)N_NODES * DH * 2);
    float*          hs       = (float*)alloc((size_t)N_NODES * DH * 4);
    unsigned*       csr2     = (unsigned*)alloc((size_t)N_EDGES * 4);
    float*          s_src    = (float*)alloc((size_t)N_NODES * 4);
    float*          s_dst    = (float*)alloc((size_t)N_NODES * 4);
    int*            row_offN = (int*)alloc((size_t)(N_NODES + 1) * 4);
    unsigned char*  deg      = (unsigned char*)alloc((size_t)NTOT + 256);
    unsigned char*  chunkOff = (unsigned char*)alloc((size_t)NTOT + 256);
    unsigned char*  rank     = (unsigned char*)alloc((size_t)N_EDGES);
    int*            degN     = (int*)alloc((size_t)N_NODES * 4);
    int*            partN    = (int*)alloc(1024 * 4);
    float*          consts   = (float*)alloc(4 * 4);

    // D1: consts | slice-LDS hist(+rank) | embed(x8)
    k_fuse1<<<1 + NB_HIST + NB_EMBED, 1024, 0, stream>>>(feats, emb_h_W, emb_h_b, h,
                                                         dst, deg, rank, emb_e_W, emb_e_b,
                                                         attn[0], attn[1], consts);
    // D2: degN + chunkOff prefix | node GEMM L1 (overlapped)
    k_fuse2<<<NB_SUMDEG + NB_NODE_T, 256, 0, stream>>>(
        deg, degN, chunkOff, h, Wself[0], Wfunc[0], attn[0], zh, hs, s_src, s_dst);
    // D3: scan1N
    k_prep3<<<NB_SCAN1N, 256, 0, stream>>>(degN, row_offN, partN);
    // D4: scan2N + tail
    k_prep4<<<1, 256, 0, stream>>>(partN, row_offN);
    // D5: scatter (1 edge/thread, direct to csr2)
    k_scat<<<NB_SCAT, 256, 0, stream>>>(src, dst, e_w, rank, row_offN, partN,
                                        chunkOff, csr2);
    // D6: agg L1
    k_agg<<<NB_AGG, 256, 0, stream>>>(row_offN, partN, csr2, s_src, s_dst, consts, 0,
                                      zh, hs, h, lin1_W, lin1_b, y, 0);
    // D7: node GEMM L2
    k_nodeL<<<NB_NODE_T, 256, 0, stream>>>(h, Wself[1], Wfunc[1], attn[1],
                                           zh, hs, s_src, s_dst);
    // D8: agg L2 + fused final projection
    k_agg<<<NB_AGG, 256, 0, stream>>>(row_offN, partN, csr2, s_src, s_dst, consts, 1,
                                      zh, hs, h, lin1_W, lin1_b, y, 1);
}

// Round 5
// 305.576 us; speedup vs baseline: 1.1104x; 1.1104x over previous
//
#include <hip/hip_runtime.h>
#include <hip/hip_fp16.h>

#define N_NODES 100000
#define N_EDGES 1600000
#define DIN 24
#define DH 64
#define DOUT 12
#define NEG_SLOPE 0.01f
#define NG 64                      // edge chunks
#define EPG (N_EDGES / NG)         // 25000 edges per chunk
#define NS 7                       // node slices for LDS hist
#define SLICE_N 16384              // nodes per slice (16 KB byte counters)
#define NTOT (NG * N_NODES)        // 6.4M (chunk,node) byte counters
#define SCAN_BLK 4096
#define LDSW 72

// role block counts
#define NB_HIST (NS * NG)                        // 448 (1024-thread blocks in D1)
#define NB_SUMDEG ((N_NODES + 255) / 256)               // 391
#define NB_SCAN1N ((N_NODES + SCAN_BLK - 1) / SCAN_BLK) // 25
#define NB_SCAT ((N_EDGES + 255) / 256)          // 6250 (1 edge/thread)
#define NB_NODE ((N_NODES + 63) / 64)            // 1563 tiles of 64 nodes
#define NB_NODE_T ((NB_NODE + 1) / 2)            // 782 blocks, 2 tiles each
#define NB_AGG ((N_NODES + 7) / 8)               // 12500

typedef _Float16 half8_t __attribute__((ext_vector_type(8)));
typedef float floatx4 __attribute__((ext_vector_type(4)));

// ---------------- role bodies ----------------
__device__ __forceinline__ void dev_consts(const float* emb_e_W, const float* emb_e_b,
                                           const float* attn1, const float* attn2,
                                           float* consts) {
    int lane = threadIdx.x;
    if (lane >= 64) return;
    float w = emb_e_W[lane], b = emb_e_b[lane];
    float a1 = attn1[2 * DH + lane], a2 = attn2[2 * DH + lane];
    float c11 = w * a1, c01 = b * a1, c12 = w * a2, c02 = b * a2;
    for (int off = 32; off; off >>= 1) {
        c11 += __shfl_down(c11, off);
        c01 += __shfl_down(c01, off);
        c12 += __shfl_down(c12, off);
        c02 += __shfl_down(c02, off);
    }
    if (lane == 0) {
        consts[0] = c11; consts[1] = c01; consts[2] = c12; consts[3] = c02;
    }
}

// slice-LDS histogram + rank capture, ZERO global atomics.
// NG=64: 448 blocks -> one full round at 2 blocks/CU (224 CUs) vs 112 before.
__device__ __forceinline__ void dev_hist(int bid, const int* dst,
                                         unsigned char* deg, unsigned char* rank) {
    __shared__ unsigned cnt[SLICE_N / 4];   // 16 KB byte-packed
    int s = bid % NS, c = bid / NS;
    for (int i = threadIdx.x; i < SLICE_N / 4; i += 1024) cnt[i] = 0;
    __syncthreads();
    int nbase = s * SLICE_N;
    int start = c * EPG, end = start + EPG;
    for (int i = start + threadIdx.x; i < end; i += 1024) {
        int local = dst[i] - nbase;
        if ((unsigned)local < SLICE_N) {
            unsigned sh = (unsigned)(local & 3) * 8u;
            unsigned old = atomicAdd(&cnt[local >> 2], 1u << sh);  // LDS atomic
            rank[i] = (unsigned char)((old >> sh) & 255u);
        }
    }
    __syncthreads();
    int nmax = N_NODES - nbase;
    if (nmax > SLICE_N) nmax = SLICE_N;
    unsigned* dw = (unsigned*)(deg + (size_t)c * N_NODES + nbase);
    for (int l = threadIdx.x; l < (nmax >> 2); l += 1024) dw[l] = cnt[l];
}

__device__ __forceinline__ void dev_scan1(int bid, const int* in, int* out,
                                          int* part, int n) {
    __shared__ int lds[256];
    int t = threadIdx.x;
    int base = bid * SCAN_BLK + t * 16;
    int v[16];
    int s = 0;
#pragma unroll
    for (int i = 0; i < 16; ++i) {
        int idx = base + i;
        v[i] = (idx < n) ? in[idx] : 0;
        s += v[i];
    }
    lds[t] = s;
    __syncthreads();
    for (int off = 1; off < 256; off <<= 1) {
        int y = (t >= off) ? lds[t - off] : 0;
        __syncthreads();
        lds[t] += y;
        __syncthreads();
    }
    int run = lds[t] - s;
#pragma unroll
    for (int i = 0; i < 16; ++i) {
        int idx = base + i;
        if (idx < n) out[idx] = run;
        run += v[i];
    }
    if (t == 255) part[bid] = lds[255];
}

// exclusive scan of part[0..nblk) + row_offN[N_NODES] tail fixup
__device__ __forceinline__ void dev_scan2(int* part, int nblk, int* row_offN) {
    __shared__ int lds2[256];
    int t = threadIdx.x;
    int v[4];
    int s = 0;
#pragma unroll
    for (int i = 0; i < 4; ++i) {
        int idx = t * 4 + i;
        v[i] = (idx < nblk) ? part[idx] : 0;
        s += v[i];
    }
    lds2[t] = s;
    __syncthreads();
    for (int off = 1; off < 256; off <<= 1) {
        int y = (t >= off) ? lds2[t - off] : 0;
        __syncthreads();
        lds2[t] += y;
        __syncthreads();
    }
    int run = lds2[t] - s;
#pragma unroll
    for (int i = 0; i < 4; ++i) {
        int idx = t * 4 + i;
        if (idx < nblk) part[idx] = run;
        run += v[i];
    }
    if (row_offN) {
        __syncthreads();
        if (t == 0) row_offN[N_NODES] = N_EDGES - part[N_NODES >> 12];
    }
}

// degN + per-node chunk prefix (byte)
__device__ __forceinline__ void dev_sumdeg(int bid, const unsigned char* degB,
                                           int* degN, unsigned char* chunkOff) {
    int n = bid * 256 + threadIdx.x;
    if (n >= N_NODES) return;
    int run = 0;
    for (int g = 0; g < NG; ++g) {
        size_t idx = (size_t)g * N_NODES + n;
        int v = (int)degB[idx];
        chunkOff[idx] = (unsigned char)run;
        run += v;
    }
    degN[n] = run;
}

// L1 node GEMM with FUSED embed: h = feats(64x24,pad32) @ Wemb^T + b computed
// per tile as a 3rd MFMA, written to global h (agg residual) AND to a per-wave
// LDS buffer in A-frag layout (same-wave write->read, no barrier needed).
// Kills the 782-block embed role in D1 and D2's 25.6MB global h re-read.
__device__ __forceinline__ void dev_nodeME(int bid, int stride,
                                           const float* feats, const float* embW,
                                           const float* embB,
                                           const float* Wself, const float* Wfunc,
                                           const float* attn,
                                           float* h, __half* zh, float* hs,
                                           float* s_src, float* s_dst) {
    __shared__ _Float16 lds[2 * 64 * LDSW];   // 18 KB layer weights
    __shared__ _Float16 wembH[64 * 40];       // 5 KB embed weights (k padded to 32, stride 40)
    __shared__ float biasS[64];
    __shared__ _Float16 hbufH[4][16 * 72];    // 9 KB per-wave h tiles (A-frag layout)
    int tid = threadIdx.x;
    for (int idx = tid; idx < 2 * 64 * 64; idx += 256) {
        int mat = idx >> 12, rem = idx & 4095;
        int o = rem >> 6, k = rem & 63;
        float v = mat ? Wfunc[rem] : Wself[rem];
        lds[(mat * 64 + o) * LDSW + k] = (_Float16)v;
    }
    for (int idx = tid; idx < 64 * 32; idx += 256) {
        int o = idx >> 5, k = idx & 31;
        wembH[o * 40 + k] = (_Float16)((k < DIN) ? embW[o * DIN + k] : 0.f);
    }
    if (tid < 64) biasS[tid] = embB[tid];
    __syncthreads();

    int wave = tid >> 6, lane = tid & 63;
    int quad = lane >> 4, lm = lane & 15;
    float asv[4], adv[4];
#pragma unroll
    for (int t = 0; t < 4; ++t) {
        asv[t] = attn[t * 16 + lm];
        adv[t] = attn[DH + t * 16 + lm];
    }
    const _Float16* bS = lds;
    const _Float16* bF = lds + 64 * LDSW;
    _Float16* hb = hbufH[wave];

    for (int tb = bid; tb < NB_NODE; tb += stride) {
        int n0 = (tb * 4 + wave) * 16;
        if (n0 >= N_NODES) continue;

        // ---- embed MFMA: A = feats rows (k = quad*8+j, valid k<24) ----
        half8_t afE;
#pragma unroll
        for (int j = 0; j < 8; ++j) afE[j] = (_Float16)0.f;
        if (quad < 3) {
            const float* f = feats + (size_t)(n0 + lm) * DIN + quad * 8;
            float4 q0 = *(const float4*)(f);
            float4 q1 = *(const float4*)(f + 4);
            afE[0] = (_Float16)q0.x; afE[1] = (_Float16)q0.y;
            afE[2] = (_Float16)q0.z; afE[3] = (_Float16)q0.w;
            afE[4] = (_Float16)q1.x; afE[5] = (_Float16)q1.y;
            afE[6] = (_Float16)q1.z; afE[7] = (_Float16)q1.w;
        }
        floatx4 accE[4];
#pragma unroll
        for (int t = 0; t < 4; ++t) accE[t] = (floatx4)0.f;
#pragma unroll
        for (int t = 0; t < 4; ++t) {
            int o = t * 16 + lm;
            half8_t bE = *(const half8_t*)(wembH + o * 40 + quad * 8);
            accE[t] = __builtin_amdgcn_mfma_f32_16x16x32_f16(afE, bE, accE[t], 0, 0, 0);
        }
        // bias + write h global (residual) + LDS hbuf (A-frag source)
#pragma unroll
        for (int t = 0; t < 4; ++t) {
            float bv = biasS[t * 16 + lm];
#pragma unroll
            for (int r = 0; r < 4; ++r) {
                float hv = accE[t][r] + bv;
                int node = n0 + quad * 4 + r;
                h[(size_t)node * DH + t * 16 + lm] = hv;
                hb[(quad * 4 + r) * 72 + t * 16 + lm] = (_Float16)hv;
            }
        }
        // same wave wrote all 16 rows of hb -> lockstep read, no barrier
        half8_t afrag[2];
#pragma unroll
        for (int ks = 0; ks < 2; ++ks)
            afrag[ks] = *(const half8_t*)(hb + lm * 72 + ks * 32 + quad * 8);

        floatx4 accS[4], accF[4];
#pragma unroll
        for (int t = 0; t < 4; ++t) { accS[t] = (floatx4)0.f; accF[t] = (floatx4)0.f; }
#pragma unroll
        for (int t = 0; t < 4; ++t) {
            int o = t * 16 + lm;
#pragma unroll
            for (int ks = 0; ks < 2; ++ks) {
                int hoff = o * LDSW + ks * 32 + quad * 8;
                half8_t b1 = *(const half8_t*)(bS + hoff);
                half8_t b2 = *(const half8_t*)(bF + hoff);
                accS[t] = __builtin_amdgcn_mfma_f32_16x16x32_f16(afrag[ks], b1, accS[t], 0, 0, 0);
                accF[t] = __builtin_amdgcn_mfma_f32_16x16x32_f16(afrag[ks], b2, accF[t], 0, 0, 0);
            }
        }

        float ps[4] = {0.f, 0.f, 0.f, 0.f}, pd[4] = {0.f, 0.f, 0.f, 0.f};
#pragma unroll
        for (int t = 0; t < 4; ++t) {
#pragma unroll
            for (int r = 0; r < 4; ++r) {
                int node = n0 + quad * 4 + r;
                float zv = accF[t][r];
                zh[(size_t)node * DH + t * 16 + lm] = __float2half(zv);
                hs[(size_t)node * DH + t * 16 + lm] = accS[t][r];
                ps[r] += zv * asv[t];
                pd[r] += zv * adv[t];
            }
        }
#pragma unroll
        for (int r = 0; r < 4; ++r) {
            float p1 = ps[r], p2 = pd[r];
            for (int off = 8; off; off >>= 1) {
                p1 += __shfl_xor(p1, off);
                p2 += __shfl_xor(p2, off);
            }
            if (lm == 0) {
                s_src[n0 + quad * 4 + r] = p1;
                s_dst[n0 + quad * 4 + r] = p2;
            }
        }
    }
}

// L2 node GEMM (reads global h), multi-tile
__device__ __forceinline__ void dev_nodeM(int bid, int stride, const float* h,
                                          const float* Wself, const float* Wfunc,
                                          const float* attn,
                                          __half* zh, float* hs,
                                          float* s_src, float* s_dst) {
    __shared__ _Float16 lds[2 * 64 * LDSW];
    int tid = threadIdx.x;
    for (int idx = tid; idx < 2 * 64 * 64; idx += 256) {
        int mat = idx >> 12, rem = idx & 4095;
        int o = rem >> 6, k = rem & 63;
        float v = mat ? Wfunc[rem] : Wself[rem];
        lds[(mat * 64 + o) * LDSW + k] = (_Float16)v;
    }
    __syncthreads();

    int wave = tid >> 6, lane = tid & 63;
    int quad = lane >> 4, lm = lane & 15;
    float asv[4], adv[4];
#pragma unroll
    for (int t = 0; t < 4; ++t) {
        asv[t] = attn[t * 16 + lm];
        adv[t] = attn[DH + t * 16 + lm];
    }
    const _Float16* bS = lds;
    const _Float16* bF = lds + 64 * LDSW;

    for (int tb = bid; tb < NB_NODE; tb += stride) {
        int n0 = (tb * 4 + wave) * 16;
        if (n0 >= N_NODES) continue;

        half8_t afrag[2];
        {
            const float4* hrow = (const float4*)(h + (size_t)(n0 + lm) * DH);
#pragma unroll
            for (int ks = 0; ks < 2; ++ks) {
                float4 p0 = hrow[ks * 8 + quad * 2];
                float4 p1 = hrow[ks * 8 + quad * 2 + 1];
                half8_t a;
                a[0] = (_Float16)p0.x; a[1] = (_Float16)p0.y;
                a[2] = (_Float16)p0.z; a[3] = (_Float16)p0.w;
                a[4] = (_Float16)p1.x; a[5] = (_Float16)p1.y;
                a[6] = (_Float16)p1.z; a[7] = (_Float16)p1.w;
                afrag[ks] = a;
            }
        }

        floatx4 accS[4], accF[4];
#pragma unroll
        for (int t = 0; t < 4; ++t) { accS[t] = (floatx4)0.f; accF[t] = (floatx4)0.f; }

#pragma unroll
        for (int t = 0; t < 4; ++t) {
            int o = t * 16 + lm;
#pragma unroll
            for (int ks = 0; ks < 2; ++ks) {
                int hoff = o * LDSW + ks * 32 + quad * 8;
                half8_t b1 = *(const half8_t*)(bS + hoff);
                half8_t b2 = *(const half8_t*)(bF + hoff);
                accS[t] = __builtin_amdgcn_mfma_f32_16x16x32_f16(afrag[ks], b1, accS[t], 0, 0, 0);
                accF[t] = __builtin_amdgcn_mfma_f32_16x16x32_f16(afrag[ks], b2, accF[t], 0, 0, 0);
            }
        }

        float ps[4] = {0.f, 0.f, 0.f, 0.f}, pd[4] = {0.f, 0.f, 0.f, 0.f};
#pragma unroll
        for (int t = 0; t < 4; ++t) {
#pragma unroll
            for (int r = 0; r < 4; ++r) {
                int node = n0 + quad * 4 + r;
                float zv = accF[t][r];
                zh[(size_t)node * DH + t * 16 + lm] = __float2half(zv);
                hs[(size_t)node * DH + t * 16 + lm] = accS[t][r];
                ps[r] += zv * asv[t];
                pd[r] += zv * adv[t];
            }
        }
#pragma unroll
        for (int r = 0; r < 4; ++r) {
            float p1 = ps[r], p2 = pd[r];
            for (int off = 8; off; off >>= 1) {
                p1 += __shfl_xor(p1, off);
                p2 += __shfl_xor(p2, off);
            }
            if (lm == 0) {
                s_src[n0 + quad * 4 + r] = p1;
                s_dst[n0 + quad * 4 + r] = p2;
            }
        }
    }
}

// ---------------- fused dispatches ----------------
// D1 (1024 thr): consts | hist only (448 blocks -> full chip round)
__global__ void __launch_bounds__(1024, 2)
k_fuse1(const int* __restrict__ dst, unsigned char* __restrict__ deg,
        unsigned char* __restrict__ rank,
        const float* __restrict__ emb_e_W, const float* __restrict__ emb_e_b,
        const float* __restrict__ attn1, const float* __restrict__ attn2,
        float* __restrict__ consts) {
    int bid = blockIdx.x;
    if (bid == 0) { dev_consts(emb_e_W, emb_e_b, attn1, attn2, consts); return; }
    dev_hist(bid - 1, dst, deg, rank);
}

// D2: node GEMM L1 + fused embed (long role first) | sumdeg+chunkOff
__global__ void __launch_bounds__(256, 4)
k_fuse2(const unsigned char* __restrict__ degB, int* __restrict__ degN,
        unsigned char* __restrict__ chunkOff,
        const float* __restrict__ feats, const float* __restrict__ embW,
        const float* __restrict__ embB,
        float* __restrict__ h, const float* __restrict__ Wself1,
        const float* __restrict__ Wfunc1, const float* __restrict__ attn1,
        __half* __restrict__ zh, float* __restrict__ hs,
        float* __restrict__ s_src, float* __restrict__ s_dst) {
    int bid = blockIdx.x;
    if (bid < NB_NODE_T) {
        dev_nodeME(bid, NB_NODE_T, feats, embW, embB, Wself1, Wfunc1, attn1,
                   h, zh, hs, s_src, s_dst);
        return;
    }
    dev_sumdeg(bid - NB_NODE_T, degB, degN, chunkOff);
}

// D3: scan1N
__global__ void k_prep3(const int* __restrict__ degN, int* __restrict__ row_offN,
                        int* __restrict__ partN) {
    dev_scan1(blockIdx.x, degN, row_offN, partN, N_NODES);
}

// D4: scan2N + tail
__global__ void k_prep4(int* __restrict__ partN, int* __restrict__ row_offN) {
    dev_scan2(partN, NB_SCAN1N, row_offN);
}

// D5: scatter, 1 edge/thread
__global__ void __launch_bounds__(256, 8)
k_scat(const int* __restrict__ src, const int* __restrict__ dst,
       const float* __restrict__ e_w, const unsigned char* __restrict__ rank,
       const int* __restrict__ row_offN, const int* __restrict__ partN,
       const unsigned char* __restrict__ chunkOff, unsigned* __restrict__ csr2) {
    int i = blockIdx.x * 256 + threadIdx.x;
    if (i >= N_EDGES) return;
    int g = i / EPG;
    int d = dst[i];
    unsigned qv = (unsigned)(e_w[i] * 32768.f);
    if (qv > 32767u) qv = 32767u;
    unsigned w = (unsigned)src[i] | (qv << 17);
    int pos = row_offN[d] + partN[d >> 12] + (int)chunkOff[(size_t)g * N_NODES + d]
            + (int)rank[i];
    csr2[pos] = w;
}

// D7: standalone layer-2 node GEMM (2 tiles/block, reads global h)
__global__ void __launch_bounds__(256, 4)
k_nodeL(const float* __restrict__ h, const float* __restrict__ Wself,
        const float* __restrict__ Wfunc, const float* __restrict__ attn,
        __half* __restrict__ zh, float* __restrict__ hs,
        float* __restrict__ s_src, float* __restrict__ s_dst) {
    dev_nodeM(blockIdx.x, NB_NODE_T, h, Wself, Wfunc, attn, zh, hs, s_src, s_dst);
}

// ---------------- fused edge softmax + aggregation + (optional) final projection --------
__global__ void k_agg(const int* __restrict__ row_off, const int* __restrict__ partN,
                      const unsigned* __restrict__ csr,
                      const float* __restrict__ s_src, const float* __restrict__ s_dstA,
                      const float* __restrict__ consts, int layer,
                      const __half* __restrict__ zh, const float* __restrict__ hsb,
                      float* __restrict__ h,
                      const float* __restrict__ lin_W, const float* __restrict__ lin_b,
                      float* __restrict__ y, int final_layer) {
    int wave = threadIdx.x >> 6, lane = threadIdx.x & 63;
    int half = lane >> 5, hl = lane & 31;
    int eg = (lane >> 3) & 3, c8 = lane & 7;
    int n = blockIdx.x * 8 + wave * 2 + half;
    if (n >= N_NODES) return;
    int rs = row_off[n] + partN[n >> 12];
    int re = row_off[n + 1] + partN[(n + 1) >> 12];
    int deg = re - rs;
    int degO = __shfl_xor(deg, 32);
    int degmax = deg > degO ? deg : degO;

    float c1 = consts[layer * 2 + 0];
    float c0 = consts[layer * 2 + 1];
    float sd = s_dstA[n];

    float acc[8];
#pragma unroll
    for (int k = 0; k < 8; ++k) acc[k] = 0.f;
    float ssl = 0.f;
    int lbase = lane & 32;

    for (int base = 0; base < degmax; base += 32) {
        float ex = 0.f;
        int s0 = 0;
        int idx = base + hl;
        if (idx < deg) {
            unsigned w = csr[rs + idx];
            s0 = (int)(w & 0x1FFFFu);
            float ew = (float)(w >> 17) * (1.f / 32768.f);
            float e = s_src[s0] + sd + ew * c1 + c0;
            e = (e > 0.f) ? e : NEG_SLOPE * e;
            ex = __expf(e);
        }
        ssl += ex;
        int cnt = degmax - base;
        if (cnt > 32) cnt = 32;
#pragma unroll 4
        for (int jb = 0; jb < cnt; jb += 4) {
            int srcl = lbase + jb + eg;
            int sj = __shfl(s0, srcl);
            float exj = __shfl(ex, srcl);
            half8_t zv = *(const half8_t*)(zh + ((size_t)sj << 6) + (c8 << 3));
#pragma unroll
            for (int k = 0; k < 8; ++k) acc[k] += exj * (float)zv[k];
        }
    }
#pragma unroll
    for (int k = 0; k < 8; ++k) {
        acc[k] += __shfl_xor(acc[k], 8);
        acc[k] += __shfl_xor(acc[k], 16);
    }
    ssl += __shfl_xor(ssl, 16); ssl += __shfl_xor(ssl, 8);
    ssl += __shfl_xor(ssl, 4);  ssl += __shfl_xor(ssl, 2);
    ssl += __shfl_xor(ssl, 1);

    const float4* hp = (const float4*)(h + (size_t)n * DH);
    float4 ho0 = hp[c8 * 2], ho1 = hp[c8 * 2 + 1];
    float hold[8] = {ho0.x, ho0.y, ho0.z, ho0.w, ho1.x, ho1.y, ho1.z, ho1.w};
    float hnew[8];
    if (deg == 0) {
#pragma unroll
        for (int k = 0; k < 8; ++k) hnew[k] = hold[k] + fmaxf(hold[k], 0.f);
    } else {
        float rinv = 1.f / ssl;
        const float4* sp = (const float4*)(hsb + (size_t)n * DH);
        float4 hs0 = sp[c8 * 2], hs1 = sp[c8 * 2 + 1];
        float hsv[8] = {hs0.x, hs0.y, hs0.z, hs0.w, hs1.x, hs1.y, hs1.z, hs1.w};
#pragma unroll
        for (int k = 0; k < 8; ++k)
            hnew[k] = hold[k] + fmaxf(hsv[k] + acc[k] * rinv, 0.f);
    }

    if (!final_layer) {
        if (eg == 0) {
            float4* op = (float4*)(h + (size_t)n * DH);
            op[c8 * 2]     = make_float4(hnew[0], hnew[1], hnew[2], hnew[3]);
            op[c8 * 2 + 1] = make_float4(hnew[4], hnew[5], hnew[6], hnew[7]);
        }
    } else {
#pragma unroll
        for (int t = 0; t < 3; ++t) {
            int o = eg * 3 + t;
            const float* wr = lin_W + o * DH + c8 * 8;
            float p = 0.f;
#pragma unroll
            for (int k = 0; k < 8; ++k) p += hnew[k] * wr[k];
            p += __shfl_xor(p, 1); p += __shfl_xor(p, 2); p += __shfl_xor(p, 4);
            if (c8 == 0) y[n * DOUT + o] = p + lin_b[o];
        }
    }
}

extern "C" void kernel_launch(void* const* d_in, const int* in_sizes, int n_in,
                              void* d_out, int out_size, void* d_ws, size_t ws_size,
                              hipStream_t stream) {
    const float* feats   = (const float*)d_in[0];
    const float* e_w     = (const float*)d_in[1];
    const int*   src     = (const int*)d_in[4];
    const int*   dst     = (const int*)d_in[5];
    const float* emb_h_W = (const float*)d_in[6];
    const float* emb_h_b = (const float*)d_in[7];
    const float* emb_e_W = (const float*)d_in[8];
    const float* emb_e_b = (const float*)d_in[9];
    const float* Wself[2] = {(const float*)d_in[10], (const float*)d_in[13]};
    const float* Wfunc[2] = {(const float*)d_in[11], (const float*)d_in[14]};
    const float* attn[2]  = {(const float*)d_in[12], (const float*)d_in[15]};
    const float* lin1_W  = (const float*)d_in[16];
    const float* lin1_b  = (const float*)d_in[17];
    float* y = (float*)d_out;

    char* ws = (char*)d_ws;
    size_t off = 0;
    auto alloc = [&](size_t bytes) {
        void* p = ws + off;
        off += (bytes + 255) & ~(size_t)255;
        return p;
    };
    float*          h        = (float*)alloc((size_t)N_NODES * DH * 4);
    __half*         zh       = (__half*)alloc((size_t)N_NODES * DH * 2);
    float*          hs       = (float*)alloc((size_t)N_NODES * DH * 4);
    unsigned*       csr2     = (unsigned*)alloc((size_t)N_EDGES * 4);
    float*          s_src    = (float*)alloc((size_t)N_NODES * 4);
    float*          s_dst    = (float*)alloc((size_t)N_NODES * 4);
    int*            row_offN = (int*)alloc((size_t)(N_NODES + 1) * 4);
    unsigned char*  deg      = (unsigned char*)alloc((size_t)NTOT + 256);
    unsigned char*  chunkOff = (unsigned char*)alloc((size_t)NTOT + 256);
    unsigned char*  rank     = (unsigned char*)alloc((size_t)N_EDGES);
    int*            degN     = (int*)alloc((size_t)N_NODES * 4);
    int*            partN    = (int*)alloc(1024 * 4);
    float*          consts   = (float*)alloc(4 * 4);

    // D1: consts | slice-LDS hist(+rank), 448 blocks
    k_fuse1<<<1 + NB_HIST, 1024, 0, stream>>>(dst, deg, rank, emb_e_W, emb_e_b,
                                              attn[0], attn[1], consts);
    // D2: node GEMM L1 (+fused embed) | degN + chunkOff prefix
    k_fuse2<<<NB_NODE_T + NB_SUMDEG, 256, 0, stream>>>(
        deg, degN, chunkOff, feats, emb_h_W, emb_h_b,
        h, Wself[0], Wfunc[0], attn[0], zh, hs, s_src, s_dst);
    // D3: scan1N
    k_prep3<<<NB_SCAN1N, 256, 0, stream>>>(degN, row_offN, partN);
    // D4: scan2N + tail
    k_prep4<<<1, 256, 0, stream>>>(partN, row_offN);
    // D5: scatter (1 edge/thread, direct to csr2)
    k_scat<<<NB_SCAT, 256, 0, stream>>>(src, dst, e_w, rank, row_offN, partN,
                                        chunkOff, csr2);
    // D6: agg L1
    k_agg<<<NB_AGG, 256, 0, stream>>>(row_offN, partN, csr2, s_src, s_dst, consts, 0,
                                      zh, hs, h, lin1_W, lin1_b, y, 0);
    // D7: node GEMM L2
    k_nodeL<<<NB_NODE_T, 256, 0, stream>>>(h, Wself[1], Wfunc[1], attn[1],
                                           zh, hs, s_src, s_dst);
    // D8: agg L2 + fused final projection
    k_agg<<<NB_AGG, 256, 0, stream>>>(row_offN, partN, csr2, s_src, s_dst, consts, 1,
                                      zh, hs, h, lin1_W, lin1_b, y, 1);
}

// Round 6
// 279.530 us; speedup vs baseline: 1.2138x; 1.0932x over previous
//
#include <hip/hip_runtime.h>
#include <hip/hip_fp16.h>

#define N_NODES 100000
#define N_EDGES 1600000
#define DIN 24
#define DH 64
#define DOUT 12
#define NEG_SLOPE 0.01f
#define NG 64                      // edge chunks
#define EPG (N_EDGES / NG)         // 25000 edges per chunk
#define NS 7                       // node slices for LDS hist
#define SLICE_N 16384              // nodes per slice (16 KB byte counters)
#define NTOT (NG * N_NODES)        // 6.4M (chunk,node) byte counters
#define SCAN_BLK 4096
#define LDSW 72

// role block counts
#define NB_HIST (NS * NG)                        // 448 (1024-thread blocks in D1)
#define NB_SUMDEG ((N_NODES + 255) / 256)               // 391
#define NB_SCAN1N ((N_NODES + SCAN_BLK - 1) / SCAN_BLK) // 25
#define NB_SCAT ((N_EDGES + 255) / 256)          // 6250 (1 edge/thread)
#define NB_NODE ((N_NODES + 63) / 64)            // 1563 tiles of 64 nodes
#define NB_NODE_T ((NB_NODE + 1) / 2)            // 782 blocks, 2 tiles each
#define NB_AGG ((N_NODES + 7) / 8)               // 12500

typedef _Float16 half8_t __attribute__((ext_vector_type(8)));
typedef float floatx4 __attribute__((ext_vector_type(4)));

// ---------------- role bodies ----------------
__device__ __forceinline__ void dev_consts(const float* emb_e_W, const float* emb_e_b,
                                           const float* attn1, const float* attn2,
                                           float* consts) {
    int lane = threadIdx.x;
    if (lane >= 64) return;
    float w = emb_e_W[lane], b = emb_e_b[lane];
    float a1 = attn1[2 * DH + lane], a2 = attn2[2 * DH + lane];
    float c11 = w * a1, c01 = b * a1, c12 = w * a2, c02 = b * a2;
    for (int off = 32; off; off >>= 1) {
        c11 += __shfl_down(c11, off);
        c01 += __shfl_down(c01, off);
        c12 += __shfl_down(c12, off);
        c02 += __shfl_down(c02, off);
    }
    if (lane == 0) {
        consts[0] = c11; consts[1] = c01; consts[2] = c12; consts[3] = c02;
    }
}

// slice-LDS histogram + rank capture, ZERO global atomics.
__device__ __forceinline__ void dev_hist(int bid, const int* dst,
                                         unsigned char* deg, unsigned char* rank) {
    __shared__ unsigned cnt[SLICE_N / 4];   // 16 KB byte-packed
    int s = bid % NS, c = bid / NS;
    for (int i = threadIdx.x; i < SLICE_N / 4; i += 1024) cnt[i] = 0;
    __syncthreads();
    int nbase = s * SLICE_N;
    int start = c * EPG, end = start + EPG;
    for (int i = start + threadIdx.x; i < end; i += 1024) {
        int local = dst[i] - nbase;
        if ((unsigned)local < SLICE_N) {
            unsigned sh = (unsigned)(local & 3) * 8u;
            unsigned old = atomicAdd(&cnt[local >> 2], 1u << sh);  // LDS atomic
            rank[i] = (unsigned char)((old >> sh) & 255u);
        }
    }
    __syncthreads();
    int nmax = N_NODES - nbase;
    if (nmax > SLICE_N) nmax = SLICE_N;
    unsigned* dw = (unsigned*)(deg + (size_t)c * N_NODES + nbase);
    for (int l = threadIdx.x; l < (nmax >> 2); l += 1024) dw[l] = cnt[l];
}

__device__ __forceinline__ void dev_scan1(int bid, const int* in, int* out,
                                          int* part, int n) {
    __shared__ int lds[256];
    int t = threadIdx.x;
    int base = bid * SCAN_BLK + t * 16;
    int v[16];
    int s = 0;
#pragma unroll
    for (int i = 0; i < 16; ++i) {
        int idx = base + i;
        v[i] = (idx < n) ? in[idx] : 0;
        s += v[i];
    }
    lds[t] = s;
    __syncthreads();
    for (int off = 1; off < 256; off <<= 1) {
        int y = (t >= off) ? lds[t - off] : 0;
        __syncthreads();
        lds[t] += y;
        __syncthreads();
    }
    int run = lds[t] - s;
#pragma unroll
    for (int i = 0; i < 16; ++i) {
        int idx = base + i;
        if (idx < n) out[idx] = run;
        run += v[i];
    }
    if (t == 255) part[bid] = lds[255];
}

// exclusive scan of part[0..nblk) + row_offN[N_NODES] tail fixup
__device__ __forceinline__ void dev_scan2(int* part, int nblk, int* row_offN) {
    __shared__ int lds2[256];
    int t = threadIdx.x;
    int v[4];
    int s = 0;
#pragma unroll
    for (int i = 0; i < 4; ++i) {
        int idx = t * 4 + i;
        v[i] = (idx < nblk) ? part[idx] : 0;
        s += v[i];
    }
    lds2[t] = s;
    __syncthreads();
    for (int off = 1; off < 256; off <<= 1) {
        int y = (t >= off) ? lds2[t - off] : 0;
        __syncthreads();
        lds2[t] += y;
        __syncthreads();
    }
    int run = lds2[t] - s;
#pragma unroll
    for (int i = 0; i < 4; ++i) {
        int idx = t * 4 + i;
        if (idx < nblk) part[idx] = run;
        run += v[i];
    }
    if (row_offN) {
        __syncthreads();
        if (t == 0) row_offN[N_NODES] = N_EDGES - part[N_NODES >> 12];
    }
}

// degN + per-node chunk prefix (byte)
__device__ __forceinline__ void dev_sumdeg(int bid, const unsigned char* degB,
                                           int* degN, unsigned char* chunkOff) {
    int n = bid * 256 + threadIdx.x;
    if (n >= N_NODES) return;
    int run = 0;
    for (int g = 0; g < NG; ++g) {
        size_t idx = (size_t)g * N_NODES + n;
        int v = (int)degB[idx];
        chunkOff[idx] = (unsigned char)run;
        run += v;
    }
    degN[n] = run;
}

// L1 node GEMM with FUSED embed; h and hs stored as f16 (round-20: agg's
// h/hs f32 streams were 51MB of its 114MB fetch; all consumers f16-tolerant).
__device__ __forceinline__ void dev_nodeME(int bid, int stride,
                                           const float* feats, const float* embW,
                                           const float* embB,
                                           const float* Wself, const float* Wfunc,
                                           const float* attn,
                                           __half* h16, __half* zh, __half* hs16,
                                           float* s_src, float* s_dst) {
    __shared__ _Float16 lds[2 * 64 * LDSW];   // 18 KB layer weights
    __shared__ _Float16 wembH[64 * 40];       // 5 KB embed weights (k pad 32, stride 40)
    __shared__ float biasS[64];
    __shared__ _Float16 hbufH[4][16 * 72];    // 9 KB per-wave h tiles (A-frag layout)
    int tid = threadIdx.x;
    for (int idx = tid; idx < 2 * 64 * 64; idx += 256) {
        int mat = idx >> 12, rem = idx & 4095;
        int o = rem >> 6, k = rem & 63;
        float v = mat ? Wfunc[rem] : Wself[rem];
        lds[(mat * 64 + o) * LDSW + k] = (_Float16)v;
    }
    for (int idx = tid; idx < 64 * 32; idx += 256) {
        int o = idx >> 5, k = idx & 31;
        wembH[o * 40 + k] = (_Float16)((k < DIN) ? embW[o * DIN + k] : 0.f);
    }
    if (tid < 64) biasS[tid] = embB[tid];
    __syncthreads();

    int wave = tid >> 6, lane = tid & 63;
    int quad = lane >> 4, lm = lane & 15;
    float asv[4], adv[4];
#pragma unroll
    for (int t = 0; t < 4; ++t) {
        asv[t] = attn[t * 16 + lm];
        adv[t] = attn[DH + t * 16 + lm];
    }
    const _Float16* bS = lds;
    const _Float16* bF = lds + 64 * LDSW;
    _Float16* hb = hbufH[wave];

    for (int tb = bid; tb < NB_NODE; tb += stride) {
        int n0 = (tb * 4 + wave) * 16;
        if (n0 >= N_NODES) continue;

        // ---- embed MFMA: A = feats rows (k = quad*8+j, valid k<24) ----
        half8_t afE;
#pragma unroll
        for (int j = 0; j < 8; ++j) afE[j] = (_Float16)0.f;
        if (quad < 3) {
            const float* f = feats + (size_t)(n0 + lm) * DIN + quad * 8;
            float4 q0 = *(const float4*)(f);
            float4 q1 = *(const float4*)(f + 4);
            afE[0] = (_Float16)q0.x; afE[1] = (_Float16)q0.y;
            afE[2] = (_Float16)q0.z; afE[3] = (_Float16)q0.w;
            afE[4] = (_Float16)q1.x; afE[5] = (_Float16)q1.y;
            afE[6] = (_Float16)q1.z; afE[7] = (_Float16)q1.w;
        }
        floatx4 accE[4];
#pragma unroll
        for (int t = 0; t < 4; ++t) accE[t] = (floatx4)0.f;
#pragma unroll
        for (int t = 0; t < 4; ++t) {
            int o = t * 16 + lm;
            half8_t bE = *(const half8_t*)(wembH + o * 40 + quad * 8);
            accE[t] = __builtin_amdgcn_mfma_f32_16x16x32_f16(afE, bE, accE[t], 0, 0, 0);
        }
        // bias + write h16 global (residual) + LDS hbuf (A-frag source)
#pragma unroll
        for (int t = 0; t < 4; ++t) {
            float bv = biasS[t * 16 + lm];
#pragma unroll
            for (int r = 0; r < 4; ++r) {
                float hv = accE[t][r] + bv;
                int node = n0 + quad * 4 + r;
                h16[(size_t)node * DH + t * 16 + lm] = __float2half(hv);
                hb[(quad * 4 + r) * 72 + t * 16 + lm] = (_Float16)hv;
            }
        }
        // same wave wrote all 16 rows of hb -> lockstep read, no barrier
        half8_t afrag[2];
#pragma unroll
        for (int ks = 0; ks < 2; ++ks)
            afrag[ks] = *(const half8_t*)(hb + lm * 72 + ks * 32 + quad * 8);

        floatx4 accS[4], accF[4];
#pragma unroll
        for (int t = 0; t < 4; ++t) { accS[t] = (floatx4)0.f; accF[t] = (floatx4)0.f; }
#pragma unroll
        for (int t = 0; t < 4; ++t) {
            int o = t * 16 + lm;
#pragma unroll
            for (int ks = 0; ks < 2; ++ks) {
                int hoff = o * LDSW + ks * 32 + quad * 8;
                half8_t b1 = *(const half8_t*)(bS + hoff);
                half8_t b2 = *(const half8_t*)(bF + hoff);
                accS[t] = __builtin_amdgcn_mfma_f32_16x16x32_f16(afrag[ks], b1, accS[t], 0, 0, 0);
                accF[t] = __builtin_amdgcn_mfma_f32_16x16x32_f16(afrag[ks], b2, accF[t], 0, 0, 0);
            }
        }

        float ps[4] = {0.f, 0.f, 0.f, 0.f}, pd[4] = {0.f, 0.f, 0.f, 0.f};
#pragma unroll
        for (int t = 0; t < 4; ++t) {
#pragma unroll
            for (int r = 0; r < 4; ++r) {
                int node = n0 + quad * 4 + r;
                float zv = accF[t][r];
                zh[(size_t)node * DH + t * 16 + lm] = __float2half(zv);
                hs16[(size_t)node * DH + t * 16 + lm] = __float2half(accS[t][r]);
                ps[r] += zv * asv[t];
                pd[r] += zv * adv[t];
            }
        }
#pragma unroll
        for (int r = 0; r < 4; ++r) {
            float p1 = ps[r], p2 = pd[r];
            for (int off = 8; off; off >>= 1) {
                p1 += __shfl_xor(p1, off);
                p2 += __shfl_xor(p2, off);
            }
            if (lm == 0) {
                s_src[n0 + quad * 4 + r] = p1;
                s_dst[n0 + quad * 4 + r] = p2;
            }
        }
    }
}

// L2 node GEMM: reads h16 directly into A-frags (no cvt chain)
__device__ __forceinline__ void dev_nodeM(int bid, int stride, const __half* h16,
                                          const float* Wself, const float* Wfunc,
                                          const float* attn,
                                          __half* zh, __half* hs16,
                                          float* s_src, float* s_dst) {
    __shared__ _Float16 lds[2 * 64 * LDSW];
    int tid = threadIdx.x;
    for (int idx = tid; idx < 2 * 64 * 64; idx += 256) {
        int mat = idx >> 12, rem = idx & 4095;
        int o = rem >> 6, k = rem & 63;
        float v = mat ? Wfunc[rem] : Wself[rem];
        lds[(mat * 64 + o) * LDSW + k] = (_Float16)v;
    }
    __syncthreads();

    int wave = tid >> 6, lane = tid & 63;
    int quad = lane >> 4, lm = lane & 15;
    float asv[4], adv[4];
#pragma unroll
    for (int t = 0; t < 4; ++t) {
        asv[t] = attn[t * 16 + lm];
        adv[t] = attn[DH + t * 16 + lm];
    }
    const _Float16* bS = lds;
    const _Float16* bF = lds + 64 * LDSW;

    for (int tb = bid; tb < NB_NODE; tb += stride) {
        int n0 = (tb * 4 + wave) * 16;
        if (n0 >= N_NODES) continue;

        const _Float16* hrow = (const _Float16*)h16 + (size_t)(n0 + lm) * DH;
        half8_t afrag[2];
#pragma unroll
        for (int ks = 0; ks < 2; ++ks)
            afrag[ks] = *(const half8_t*)(hrow + ks * 32 + quad * 8);

        floatx4 accS[4], accF[4];
#pragma unroll
        for (int t = 0; t < 4; ++t) { accS[t] = (floatx4)0.f; accF[t] = (floatx4)0.f; }

#pragma unroll
        for (int t = 0; t < 4; ++t) {
            int o = t * 16 + lm;
#pragma unroll
            for (int ks = 0; ks < 2; ++ks) {
                int hoff = o * LDSW + ks * 32 + quad * 8;
                half8_t b1 = *(const half8_t*)(bS + hoff);
                half8_t b2 = *(const half8_t*)(bF + hoff);
                accS[t] = __builtin_amdgcn_mfma_f32_16x16x32_f16(afrag[ks], b1, accS[t], 0, 0, 0);
                accF[t] = __builtin_amdgcn_mfma_f32_16x16x32_f16(afrag[ks], b2, accF[t], 0, 0, 0);
            }
        }

        float ps[4] = {0.f, 0.f, 0.f, 0.f}, pd[4] = {0.f, 0.f, 0.f, 0.f};
#pragma unroll
        for (int t = 0; t < 4; ++t) {
#pragma unroll
            for (int r = 0; r < 4; ++r) {
                int node = n0 + quad * 4 + r;
                float zv = accF[t][r];
                zh[(size_t)node * DH + t * 16 + lm] = __float2half(zv);
                hs16[(size_t)node * DH + t * 16 + lm] = __float2half(accS[t][r]);
                ps[r] += zv * asv[t];
                pd[r] += zv * adv[t];
            }
        }
#pragma unroll
        for (int r = 0; r < 4; ++r) {
            float p1 = ps[r], p2 = pd[r];
            for (int off = 8; off; off >>= 1) {
                p1 += __shfl_xor(p1, off);
                p2 += __shfl_xor(p2, off);
            }
            if (lm == 0) {
                s_src[n0 + quad * 4 + r] = p1;
                s_dst[n0 + quad * 4 + r] = p2;
            }
        }
    }
}

// ---------------- fused dispatches ----------------
// D1 (1024 thr): consts | hist only (448 blocks -> full chip round)
__global__ void __launch_bounds__(1024, 2)
k_fuse1(const int* __restrict__ dst, unsigned char* __restrict__ deg,
        unsigned char* __restrict__ rank,
        const float* __restrict__ emb_e_W, const float* __restrict__ emb_e_b,
        const float* __restrict__ attn1, const float* __restrict__ attn2,
        float* __restrict__ consts) {
    int bid = blockIdx.x;
    if (bid == 0) { dev_consts(emb_e_W, emb_e_b, attn1, attn2, consts); return; }
    dev_hist(bid - 1, dst, deg, rank);
}

// D2: node GEMM L1 + fused embed (long role first) | sumdeg+chunkOff
__global__ void __launch_bounds__(256, 4)
k_fuse2(const unsigned char* __restrict__ degB, int* __restrict__ degN,
        unsigned char* __restrict__ chunkOff,
        const float* __restrict__ feats, const float* __restrict__ embW,
        const float* __restrict__ embB,
        __half* __restrict__ h16, const float* __restrict__ Wself1,
        const float* __restrict__ Wfunc1, const float* __restrict__ attn1,
        __half* __restrict__ zh, __half* __restrict__ hs16,
        float* __restrict__ s_src, float* __restrict__ s_dst) {
    int bid = blockIdx.x;
    if (bid < NB_NODE_T) {
        dev_nodeME(bid, NB_NODE_T, feats, embW, embB, Wself1, Wfunc1, attn1,
                   h16, zh, hs16, s_src, s_dst);
        return;
    }
    dev_sumdeg(bid - NB_NODE_T, degB, degN, chunkOff);
}

// D3: scan1N
__global__ void k_prep3(const int* __restrict__ degN, int* __restrict__ row_offN,
                        int* __restrict__ partN) {
    dev_scan1(blockIdx.x, degN, row_offN, partN, N_NODES);
}

// D4: scan2N + tail
__global__ void k_prep4(int* __restrict__ partN, int* __restrict__ row_offN) {
    dev_scan2(partN, NB_SCAN1N, row_offN);
}

// D5: scatter, 1 edge/thread
__global__ void __launch_bounds__(256, 8)
k_scat(const int* __restrict__ src, const int* __restrict__ dst,
       const float* __restrict__ e_w, const unsigned char* __restrict__ rank,
       const int* __restrict__ row_offN, const int* __restrict__ partN,
       const unsigned char* __restrict__ chunkOff, unsigned* __restrict__ csr2) {
    int i = blockIdx.x * 256 + threadIdx.x;
    if (i >= N_EDGES) return;
    int g = i / EPG;
    int d = dst[i];
    unsigned qv = (unsigned)(e_w[i] * 32768.f);
    if (qv > 32767u) qv = 32767u;
    unsigned w = (unsigned)src[i] | (qv << 17);
    int pos = row_offN[d] + partN[d >> 12] + (int)chunkOff[(size_t)g * N_NODES + d]
            + (int)rank[i];
    csr2[pos] = w;
}

// D7: standalone layer-2 node GEMM (2 tiles/block, reads h16)
__global__ void __launch_bounds__(256, 4)
k_nodeL(const __half* __restrict__ h16, const float* __restrict__ Wself,
        const float* __restrict__ Wfunc, const float* __restrict__ attn,
        __half* __restrict__ zh, __half* __restrict__ hs16,
        float* __restrict__ s_src, float* __restrict__ s_dst) {
    dev_nodeM(blockIdx.x, NB_NODE_T, h16, Wself, Wfunc, attn, zh, hs16, s_src, s_dst);
}

// ---------------- fused edge softmax + aggregation + (optional) final projection --------
__global__ void k_agg(const int* __restrict__ row_off, const int* __restrict__ partN,
                      const unsigned* __restrict__ csr,
                      const float* __restrict__ s_src, const float* __restrict__ s_dstA,
                      const float* __restrict__ consts, int layer,
                      const __half* __restrict__ zh, const __half* __restrict__ hsb,
                      __half* __restrict__ h16,
                      const float* __restrict__ lin_W, const float* __restrict__ lin_b,
                      float* __restrict__ y, int final_layer) {
    int wave = threadIdx.x >> 6, lane = threadIdx.x & 63;
    int half = lane >> 5, hl = lane & 31;
    int eg = (lane >> 3) & 3, c8 = lane & 7;
    int n = blockIdx.x * 8 + wave * 2 + half;
    if (n >= N_NODES) return;
    int rs = row_off[n] + partN[n >> 12];
    int re = row_off[n + 1] + partN[(n + 1) >> 12];
    int deg = re - rs;
    int degO = __shfl_xor(deg, 32);
    int degmax = deg > degO ? deg : degO;

    float c1 = consts[layer * 2 + 0];
    float c0 = consts[layer * 2 + 1];
    float sd = s_dstA[n];

    float acc[8];
#pragma unroll
    for (int k = 0; k < 8; ++k) acc[k] = 0.f;
    float ssl = 0.f;
    int lbase = lane & 32;

    for (int base = 0; base < degmax; base += 32) {
        float ex = 0.f;
        int s0 = 0;
        int idx = base + hl;
        if (idx < deg) {
            unsigned w = csr[rs + idx];
            s0 = (int)(w & 0x1FFFFu);
            float ew = (float)(w >> 17) * (1.f / 32768.f);
            float e = s_src[s0] + sd + ew * c1 + c0;
            e = (e > 0.f) ? e : NEG_SLOPE * e;
            ex = __expf(e);
        }
        ssl += ex;
        int cnt = degmax - base;
        if (cnt > 32) cnt = 32;
#pragma unroll 4
        for (int jb = 0; jb < cnt; jb += 4) {
            int srcl = lbase + jb + eg;
            int sj = __shfl(s0, srcl);
            float exj = __shfl(ex, srcl);
            half8_t zv = *(const half8_t*)((const _Float16*)zh + ((size_t)sj << 6) + (c8 << 3));
#pragma unroll
            for (int k = 0; k < 8; ++k) acc[k] += exj * (float)zv[k];
        }
    }
#pragma unroll
    for (int k = 0; k < 8; ++k) {
        acc[k] += __shfl_xor(acc[k], 8);
        acc[k] += __shfl_xor(acc[k], 16);
    }
    ssl += __shfl_xor(ssl, 16); ssl += __shfl_xor(ssl, 8);
    ssl += __shfl_xor(ssl, 4);  ssl += __shfl_xor(ssl, 2);
    ssl += __shfl_xor(ssl, 1);

    half8_t hv8 = *(const half8_t*)((const _Float16*)h16 + (size_t)n * DH + (c8 << 3));
    float hold[8];
#pragma unroll
    for (int k = 0; k < 8; ++k) hold[k] = (float)hv8[k];
    float hnew[8];
    if (deg == 0) {
#pragma unroll
        for (int k = 0; k < 8; ++k) hnew[k] = hold[k] + fmaxf(hold[k], 0.f);
    } else {
        float rinv = 1.f / ssl;
        half8_t hs8 = *(const half8_t*)((const _Float16*)hsb + (size_t)n * DH + (c8 << 3));
#pragma unroll
        for (int k = 0; k < 8; ++k)
            hnew[k] = hold[k] + fmaxf((float)hs8[k] + acc[k] * rinv, 0.f);
    }

    if (!final_layer) {
        if (eg == 0) {
            half8_t o8;
#pragma unroll
            for (int k = 0; k < 8; ++k) o8[k] = (_Float16)hnew[k];
            *(half8_t*)((_Float16*)h16 + (size_t)n * DH + (c8 << 3)) = o8;
        }
    } else {
#pragma unroll
        for (int t = 0; t < 3; ++t) {
            int o = eg * 3 + t;
            const float* wr = lin_W + o * DH + c8 * 8;
            float p = 0.f;
#pragma unroll
            for (int k = 0; k < 8; ++k) p += hnew[k] * wr[k];
            p += __shfl_xor(p, 1); p += __shfl_xor(p, 2); p += __shfl_xor(p, 4);
            if (c8 == 0) y[n * DOUT + o] = p + lin_b[o];
        }
    }
}

extern "C" void kernel_launch(void* const* d_in, const int* in_sizes, int n_in,
                              void* d_out, int out_size, void* d_ws, size_t ws_size,
                              hipStream_t stream) {
    const float* feats   = (const float*)d_in[0];
    const float* e_w     = (const float*)d_in[1];
    const int*   src     = (const int*)d_in[4];
    const int*   dst     = (const int*)d_in[5];
    const float* emb_h_W = (const float*)d_in[6];
    const float* emb_h_b = (const float*)d_in[7];
    const float* emb_e_W = (const float*)d_in[8];
    const float* emb_e_b = (const float*)d_in[9];
    const float* Wself[2] = {(const float*)d_in[10], (const float*)d_in[13]};
    const float* Wfunc[2] = {(const float*)d_in[11], (const float*)d_in[14]};
    const float* attn[2]  = {(const float*)d_in[12], (const float*)d_in[15]};
    const float* lin1_W  = (const float*)d_in[16];
    const float* lin1_b  = (const float*)d_in[17];
    float* y = (float*)d_out;

    char* ws = (char*)d_ws;
    size_t off = 0;
    auto alloc = [&](size_t bytes) {
        void* p = ws + off;
        off += (bytes + 255) & ~(size_t)255;
        return p;
    };
    __half*         h16      = (__half*)alloc((size_t)N_NODES * DH * 2);
    __half*         zh       = (__half*)alloc((size_t)N_NODES * DH * 2);
    __half*         hs16     = (__half*)alloc((size_t)N_NODES * DH * 2);
    unsigned*       csr2     = (unsigned*)alloc((size_t)N_EDGES * 4);
    float*          s_src    = (float*)alloc((size_t)N_NODES * 4);
    float*          s_dst    = (float*)alloc((size_t)N_NODES * 4);
    int*            row_offN = (int*)alloc((size_t)(N_NODES + 1) * 4);
    unsigned char*  deg      = (unsigned char*)alloc((size_t)NTOT + 256);
    unsigned char*  chunkOff = (unsigned char*)alloc((size_t)NTOT + 256);
    unsigned char*  rank     = (unsigned char*)alloc((size_t)N_EDGES);
    int*            degN     = (int*)alloc((size_t)N_NODES * 4);
    int*            partN    = (int*)alloc(1024 * 4);
    float*          consts   = (float*)alloc(4 * 4);

    // D1: consts | slice-LDS hist(+rank), 448 blocks
    k_fuse1<<<1 + NB_HIST, 1024, 0, stream>>>(dst, deg, rank, emb_e_W, emb_e_b,
                                              attn[0], attn[1], consts);
    // D2: node GEMM L1 (+fused embed) | degN + chunkOff prefix
    k_fuse2<<<NB_NODE_T + NB_SUMDEG, 256, 0, stream>>>(
        deg, degN, chunkOff, feats, emb_h_W, emb_h_b,
        h16, Wself[0], Wfunc[0], attn[0], zh, hs16, s_src, s_dst);
    // D3: scan1N
    k_prep3<<<NB_SCAN1N, 256, 0, stream>>>(degN, row_offN, partN);
    // D4: scan2N + tail
    k_prep4<<<1, 256, 0, stream>>>(partN, row_offN);
    // D5: scatter (1 edge/thread, direct to csr2)
    k_scat<<<NB_SCAT, 256, 0, stream>>>(src, dst, e_w, rank, row_offN, partN,
                                        chunkOff, csr2);
    // D6: agg L1
    k_agg<<<NB_AGG, 256, 0, stream>>>(row_offN, partN, csr2, s_src, s_dst, consts, 0,
                                      zh, hs16, h16, lin1_W, lin1_b, y, 0);
    // D7: node GEMM L2
    k_nodeL<<<NB_NODE_T, 256, 0, stream>>>(h16, Wself[1], Wfunc[1], attn[1],
                                           zh, hs16, s_src, s_dst);
    // D8: agg L2 + fused final projection
    k_agg<<<NB_AGG, 256, 0, stream>>>(row_offN, partN, csr2, s_src, s_dst, consts, 1,
                                      zh, hs16, h16, lin1_W, lin1_b, y, 1);
}